// Round 14
// baseline (232.377 us; speedup 1.0000x reference)
//
#include <hip/hip_runtime.h>
#include <math.h>

// SPGG Fermi update, L=4096 periodic lattice — lane-local v6.
// v5 -> v6: restore deep MLP (the only lever that ever raised achieved BW:
// R6 hit 3.37 TB/s with 2-row batched loads; v5's 1-row schedule fell back
// to 2.15 TB/s). Two output rows per iteration; 10 loads (2 t-rows, 2 lp,
// 2 dir) issued at iteration top, consumed next iteration (depth-2 pipe).
// Fully unrolled; fermi rows keep slim t-state (center + 2 edge floats).
// Traffic stays minimal (v5 fixed write amplification: WRITE=64MB exact).
// f32 op order identical per site to the verified absmax-0.0 kernels.

#define LSZ 4096
#define LMASK 4095
#define BANDH 8          // rows per wave

typedef float v4f __attribute__((ext_vector_type(4)));
typedef int   v4i __attribute__((ext_vector_type(4)));

struct R12 { v4f l, c, r; };          // t cols c-4..c-1, c..c+3, c+4..c+7
struct A8  { v4f lo, hi; };           // a cols c-2..c+1, c+2..c+5
struct P6  { v4f lo; float p3, p4; }; // p cols c-1..c+2, c+3, c+4

// n*0.2f*3.0f is bit-identical to n/5.0f*3.0f for all n in {0..5}
#define AMUL(n) (((n) * 0.2f) * 3.0f)

__device__ __forceinline__ A8 a_row(const R12& tm, const R12& tc, const R12& tp) {
    A8 a;
    // reference order: ((((center + up) + down) + left) + right)
    a.lo.x = AMUL((((tc.l.z + tm.l.z) + tp.l.z) + tc.l.y) + tc.l.w); // j=-2
    a.lo.y = AMUL((((tc.l.w + tm.l.w) + tp.l.w) + tc.l.z) + tc.c.x); // j=-1
    a.lo.z = AMUL((((tc.c.x + tm.c.x) + tp.c.x) + tc.l.w) + tc.c.y); // j= 0
    a.lo.w = AMUL((((tc.c.y + tm.c.y) + tp.c.y) + tc.c.x) + tc.c.z); // j= 1
    a.hi.x = AMUL((((tc.c.z + tm.c.z) + tp.c.z) + tc.c.y) + tc.c.w); // j= 2
    a.hi.y = AMUL((((tc.c.w + tm.c.w) + tp.c.w) + tc.c.z) + tc.r.x); // j= 3
    a.hi.z = AMUL((((tc.r.x + tm.r.x) + tp.r.x) + tc.c.w) + tc.r.y); // j= 4
    a.hi.w = AMUL((((tc.r.y + tm.r.y) + tp.r.y) + tc.r.x) + tc.r.z); // j= 5
    return a;
}

__device__ __forceinline__ float pcol(float aC, float aU, float aD,
                                      float aL, float aR, float tv) {
    float d5 = (((aC + aU) + aD) + aL) + aR;
    float c5 = ((((aC - 1.0f) + (aU - 1.0f)) + (aD - 1.0f))
                + (aL - 1.0f)) + (aR - 1.0f);
    return (tv == 1.0f) ? c5 : d5;
}

__device__ __forceinline__ P6 p_row(const A8& am, const A8& ac, const A8& ap,
                                    const R12& tc) {
    P6 p;
    p.lo.x = pcol(ac.lo.y, am.lo.y, ap.lo.y, ac.lo.x, ac.lo.z, tc.l.w); // j=-1
    p.lo.y = pcol(ac.lo.z, am.lo.z, ap.lo.z, ac.lo.y, ac.lo.w, tc.c.x); // j= 0
    p.lo.z = pcol(ac.lo.w, am.lo.w, ap.lo.w, ac.lo.z, ac.hi.x, tc.c.y); // j= 1
    p.lo.w = pcol(ac.hi.x, am.hi.x, ap.hi.x, ac.lo.w, ac.hi.y, tc.c.z); // j= 2
    p.p3   = pcol(ac.hi.y, am.hi.y, ap.hi.y, ac.hi.x, ac.hi.z, tc.c.w); // j= 3
    p.p4   = pcol(ac.hi.z, am.hi.z, ap.hi.z, ac.hi.y, ac.hi.w, tc.r.x); // j= 4
    return p;
}

__device__ __forceinline__ float fermi(float pc, float pnl, float pnr, float pnu, float pnd,
                                       float tc, float tnl, float tnr, float tnu, float tnd,
                                       float lpx, int k) {
    float pn = (k == 0) ? pnl : (k == 1) ? pnr : (k == 2) ? pnu : pnd;
    float tn = (k == 0) ? tnl : (k == 1) ? tnr : (k == 2) ? tnu : tnd;
    float d  = pc - pn;
    // fast path (rel err ~1e-5) with conservative uncertainty band
    float ef = __expf(d * 10.0f);
    float Wf = __builtin_amdgcn_rcpf(1.0f + ef);
    float eps = 1e-4f * Wf + 1e-37f;
    float res;
    if (lpx <= Wf - eps)      res = tn;
    else if (lpx > Wf + eps)  res = tc;
    else {
        // bit-exact reference path (verified absmax 0.0 in rounds 1-2-5-6-8-11)
        float arg = d / 0.1f;
        float e = (float)exp((double)arg);
        float W = 1.0f / (1.0f + e);
        res = (lpx <= W) ? tn : tc;
    }
    return res;
}

__global__ __launch_bounds__(256, 3) void spgg_fermi_kernel(
    const float* __restrict__ t,       // type matrix, 0.0/1.0
    const float* __restrict__ lp,      // learning probabilities
    const int*   __restrict__ dir,     // learning direction 0..3
    float* __restrict__ out)
{
    const int lane = threadIdx.x & 63;
    const int wv   = threadIdx.x >> 6;

    // bijective XCD swizzle: nwg = 2048 = 8 * 256; XCD x owns strips 2x, 2x+1
    const int orig = blockIdx.x;
    const int e    = (orig & 7) * 256 + (orig >> 3);
    const int s    = e >> 7;                   // strip 0..15
    const int bg   = e & 127;                  // 0..127
    const int band = bg * 4 + wv;              // 0..511
    const int r0   = band * BANDH;
    const int col  = s * 256 + 4 * lane;       // exact tiling, 16B aligned
    const int colL = (col - 4) & LMASK;
    const int colR = (col + 4) & LMASK;

    auto ldR = [&](int r_) -> R12 {
        const int base = (r_ & LMASK) << 12;
        R12 x;
        x.l = *(const v4f*)&t[base + colL];
        x.c = *(const v4f*)&t[base + col];
        x.r = *(const v4f*)&t[base + colR];
        return x;
    };
    auto ldLP = [&](int r_) -> v4f {
        return *(const v4f*)&lp[((r_ & LMASK) << 12) + col];
    };
    auto ldDR = [&](int r_) -> v4i {
        return *(const v4i*)&dir[((r_ & LMASK) << 12) + col];
    };

    // ---- warmup: fill pipeline for output rows r0, r0+1 ----
    R12 w3 = ldR(r0 - 3), w2 = ldR(r0 - 2), w1 = ldR(r0 - 1), w0 = ldR(r0);
    R12 G1 = ldR(r0 + 1), G2 = ldR(r0 + 2), G3 = ldR(r0 + 3), G4 = ldR(r0 + 4);
    v4f LPa = ldLP(r0), LPb = ldLP(r0 + 1);
    v4i DRa = ldDR(r0), DRb = ldDR(r0 + 1);

    A8 aM2 = a_row(w3, w2, w1);         // a(r0-2)
    A8 aM1 = a_row(w2, w1, w0);         // a(r0-1)
    A8 A0  = a_row(w1, w0, G1);         // a(r0)
    A8 A1  = a_row(w0, G1, G2);         // a(r0+1)
    P6 P0  = p_row(aM2, aM1, A0, w1);   // p(r0-1)
    P6 P1  = p_row(aM1, A0, A1, w0);    // p(r0)

    v4f  Cm1 = w1.c;                    // t(r-1) center (up-neighbor, row r)
    v4f  S0c = w0.c;                    // t(r) center
    float S0lw = w0.l.w, S0rx = w0.r.x; // t(r) left/right edge neighbors

    // ---- main loop: TWO output rows per iteration, 10 loads batched ----
    #pragma unroll
    for (int ii = 0; ii < BANDH; ii += 2) {
        const int r = r0 + ii;

        // all consumed NEXT iteration (depth-2 pipeline)
        R12 G5  = ldR(r + 5);
        R12 G6  = ldR(r + 6);
        v4f LPn2 = ldLP(r + 2), LPn3 = ldLP(r + 3);
        v4i DRn2 = ldDR(r + 2), DRn3 = ldDR(r + 3);

        A8 A2 = a_row(G1, G2, G3);          // a(r+2)
        A8 A3 = a_row(G2, G3, G4);          // a(r+3)
        P6 P2 = p_row(A0, A1, A2, G1);      // p(r+1)
        P6 P3 = p_row(A1, A2, A3, G2);      // p(r+2)

        // ---- output row r ----
        {
            v4f o;
            o.x = fermi(P1.lo.y, P1.lo.x, P1.lo.z, P0.lo.y, P2.lo.y,
                        S0c.x, S0lw,  S0c.y, Cm1.x, G1.c.x, LPa.x, DRa.x);
            o.y = fermi(P1.lo.z, P1.lo.y, P1.lo.w, P0.lo.z, P2.lo.z,
                        S0c.y, S0c.x, S0c.z, Cm1.y, G1.c.y, LPa.y, DRa.y);
            o.z = fermi(P1.lo.w, P1.lo.z, P1.p3,  P0.lo.w, P2.lo.w,
                        S0c.z, S0c.y, S0c.w, Cm1.z, G1.c.z, LPa.z, DRa.z);
            o.w = fermi(P1.p3,  P1.lo.w, P1.p4,  P0.p3,  P2.p3,
                        S0c.w, S0c.z, S0rx,  Cm1.w, G1.c.w, LPa.w, DRa.w);
            *(v4f*)&out[(r << 12) + col] = o;
        }

        // ---- output row r+1 ----
        {
            v4f o;
            o.x = fermi(P2.lo.y, P2.lo.x, P2.lo.z, P1.lo.y, P3.lo.y,
                        G1.c.x, G1.l.w, G1.c.y, S0c.x, G2.c.x, LPb.x, DRb.x);
            o.y = fermi(P2.lo.z, P2.lo.y, P2.lo.w, P1.lo.z, P3.lo.z,
                        G1.c.y, G1.c.x, G1.c.z, S0c.y, G2.c.y, LPb.y, DRb.y);
            o.z = fermi(P2.lo.w, P2.lo.z, P2.p3,  P1.lo.w, P3.lo.w,
                        G1.c.z, G1.c.y, G1.c.w, S0c.z, G2.c.z, LPb.z, DRb.z);
            o.w = fermi(P2.p3,  P2.lo.w, P2.p4,  P1.p3,  P3.p3,
                        G1.c.w, G1.c.z, G1.r.x, S0c.w, G2.c.w, LPb.w, DRb.w);
            *(v4f*)&out[((r + 1) << 12) + col] = o;
        }

        // ---- rotate pipeline state by 2 rows ----
        Cm1 = G1.c;
        S0c = G2.c; S0lw = G2.l.w; S0rx = G2.r.x;
        G1 = G3; G2 = G4; G3 = G5; G4 = G6;
        A0 = A2; A1 = A3;
        P0 = P2; P1 = P3;
        LPa = LPn2; DRa = DRn2;
        LPb = LPn3; DRb = DRn3;
    }
}

extern "C" void kernel_launch(void* const* d_in, const int* in_sizes, int n_in,
                              void* d_out, int out_size, void* d_ws, size_t ws_size,
                              hipStream_t stream)
{
    const float* t   = (const float*)d_in[0];
    const float* lp  = (const float*)d_in[1];
    const int*   dir = (const int*)d_in[2];
    float* out = (float*)d_out;

    // 16 strips x 128 block-groups (4 waves/block = 4 bands of 8 rows)
    dim3 grid(16 * 128);   // 2048 blocks
    dim3 block(256);
    hipLaunchKernelGGL(spgg_fermi_kernel, grid, block, 0, stream, t, lp, dir, out);
}